// Round 8
// baseline (338.496 us; speedup 1.0000x reference)
//
#include <hip/hip_runtime.h>

#define N_NODES 50000
#define N_EDGES 800000
#define IN_DIM 128
#define EMB_DIM 64
#define HID 128
#define OUT_DIM 64
#define NUM_GRAPHS 128
#define E_TOT (N_EDGES + N_NODES)
#define K1 (IN_DIM + EMB_DIM)   // 192
#define BSH 8                    // bucket = 256 dst nodes
#define BNODES 256
#define NB 196                   // ceil(N_NODES/256)
#define EPT 16
#define EPB (256 * EPT)          // 4096 edges per passA block
#define PREPA_BLOCKS 3125        // 16 nodes per block
#define BHIST_BLOCKS 512
#define PB_CAP 5376              // passB LDS staging capacity
#define AGGR_BLOCKS 3125         // 16 nodes per block (4 waves x 4 nodes)

typedef __attribute__((ext_vector_type(8))) short bf16x8;
typedef __attribute__((ext_vector_type(4))) float f32x4;

__device__ __forceinline__ float gelu_f(float x) {
    float x3 = x * x * x;
    return 0.5f * x * (1.0f + tanhf(0.7978845608028654f * (x + 0.044715f * x3)));
}
__device__ __forceinline__ float lrelu02(float x) { return x > 0.f ? x : 0.2f * x; }
__device__ __forceinline__ float rl_f(float v, int j) {
    return __int_as_float(__builtin_amdgcn_readlane(__float_as_int(v), j));
}
__device__ __forceinline__ unsigned short f2bf(float f) {  // RNE
    unsigned u = __float_as_uint(f);
    unsigned r = (u + 0x7fffu + ((u >> 16) & 1u)) >> 16;
    return (unsigned short)r;
}
__device__ __forceinline__ unsigned pk2bf(float a, float b) {
    return (unsigned)f2bf(a) | ((unsigned)f2bf(b) << 16);
}

// ---------- prep all three W^T bf16 padded; last block zeroes bcnt/bfill ----------
__global__ __launch_bounds__(128) void k_prepW3(const float* __restrict__ W1, unsigned short* __restrict__ Wt1,
                                                const float* __restrict__ W2, unsigned short* __restrict__ Wt2,
                                                const float* __restrict__ W3, unsigned short* __restrict__ Wt3,
                                                int* __restrict__ bcnt, int* __restrict__ bfill) {
    int b = blockIdx.x;
    int c = threadIdx.x;
    if (b == K1 + 2 * HID) {
        for (int i = c; i < NB; i += 128) { bcnt[i] = 0; bfill[i] = 0; }
        return;
    }
    if (b < K1) {
        Wt1[(size_t)c * (K1 + 8) + b] = f2bf(W1[(size_t)b * HID + c]);
    } else if (b < K1 + HID) {
        int k = b - K1;
        Wt2[(size_t)c * (HID + 8) + k] = f2bf(W2[(size_t)k * HID + c]);
    } else {
        int k = b - K1 - HID;
        Wt3[(size_t)c * (HID + 8) + k] = f2bf(W3[(size_t)k * HID + c]);
    }
}

// ---------- prep A: 16 nodes/block (4 waves x 4 nodes) + bucket histogram tail ----------
__global__ __launch_bounds__(256) void k_prepA_bhist(const float* __restrict__ x, const int* __restrict__ nidx,
                                                     const float* __restrict__ emb, unsigned* __restrict__ Abu,
                                                     const int* __restrict__ dst, int* __restrict__ bcnt) {
    __shared__ int h[NB];
    if (blockIdx.x >= PREPA_BLOCKS) {
        int nb = blockIdx.x - PREPA_BLOCKS;
        for (int i = threadIdx.x; i < NB; i += 256) h[i] = 0;
        __syncthreads();
        for (int e = nb * 256 + threadIdx.x; e < N_EDGES; e += BHIST_BLOCKS * 256)
            atomicAdd(&h[dst[e] >> BSH], 1);
        __syncthreads();
        for (int i = threadIdx.x; i < NB; i += 256)
            if (h[i]) atomicAdd(&bcnt[i], h[i]);
        return;
    }
    int lane = threadIdx.x & 63;
    int wv = threadIdx.x >> 6;
    int nodeBase = blockIdx.x * 16 + wv * 4;
#pragma unroll
    for (int it = 0; it < 4; it++) {
        int node = nodeBase + it;
        if (node >= N_NODES) break;
        int nid = nidx[node];  // issue early: overlaps with x-row load below
        float2 v = ((const float2*)(x + (size_t)node * IN_DIM))[lane];
        float ss = v.x * v.x + v.y * v.y;
#pragma unroll
        for (int o = 32; o; o >>= 1) ss += __shfl_xor(ss, o);
        float nrm = sqrtf(ss);
        if (nrm == 0.f) nrm = 1e-8f;
        float inv = 1.f / nrm;
        unsigned* row = Abu + (size_t)node * (K1 / 2);
        row[lane] = pk2bf(v.x * inv, v.y * inv);
        nid = __builtin_amdgcn_readfirstlane(nid);
        if (lane < 32) {
            float2 e = ((const float2*)(emb + (size_t)nid * EMB_DIM))[lane];
            row[64 + lane] = pk2bf(e.x, e.y);
        }
    }
}

// ---------- pass A: partition edges bucket-major; local scan (bscan folded in) ----------
__global__ __launch_bounds__(256) void k_passA(const int* __restrict__ src, const int* __restrict__ dst,
                                               const int* __restrict__ bcnt, int* __restrict__ boff,
                                               int* __restrict__ bfill, unsigned* __restrict__ barr) {
    __shared__ int h[NB];
    __shared__ int hbase[NB];
    __shared__ int lofs[NB];
    __shared__ int gbo[NB];      // global bucket offsets (local scan of bcnt)
    __shared__ int ssc[256];
    __shared__ unsigned val[EPB];
    __shared__ unsigned char bid[EPB];
    int t = threadIdx.x;
    for (int i = t; i < NB; i += 256) h[i] = 0;
    // scan bcnt -> gbo (every block computes identical result; replaces k_bscan)
    int gv = (t < NB) ? bcnt[t] : 0;
    ssc[t] = gv;
    __syncthreads();
    for (int o = 1; o < 256; o <<= 1) {
        int u = (t >= o) ? ssc[t - o] : 0;
        __syncthreads();
        ssc[t] += u;
        __syncthreads();
    }
    if (t < NB) gbo[t] = ssc[t] - gv;
    if (blockIdx.x == 0) {
        if (t < NB) boff[t] = ssc[t] - gv;
        if (t == NB - 1) boff[NB] = ssc[t];
    }
    __syncthreads();
    int e0 = blockIdx.x * EPB;
    int tag[EPT];
#pragma unroll
    for (int i = 0; i < EPT; i++) {
        int e = e0 + i * 256 + t;
        tag[i] = -1;
        if (e < N_EDGES) {
            int b = dst[e] >> BSH;
            int r = atomicAdd(&h[b], 1);  // rank within (block,bucket); r < 4096
            tag[i] = (b << 12) | r;
        }
    }
    __syncthreads();
    // exclusive scan of per-bucket LOCAL counts -> local offsets; claim global chunks
    int v = (t < NB) ? h[t] : 0;
    ssc[t] = v;
    __syncthreads();
    for (int o = 1; o < 256; o <<= 1) {
        int u = (t >= o) ? ssc[t - o] : 0;
        __syncthreads();
        ssc[t] += u;
        __syncthreads();
    }
    if (t < NB) {
        lofs[t] = ssc[t] - v;
        hbase[t] = v ? atomicAdd(&bfill[t], v) : 0;
    }
    __syncthreads();
    int tot = ssc[255];
    // scatter into LDS (bucket-major within block)
#pragma unroll
    for (int i = 0; i < EPT; i++) {
        if (tag[i] >= 0) {
            int e = e0 + i * 256 + t;
            int b = tag[i] >> 12, r = tag[i] & 0xfff;
            unsigned s = (unsigned)src[e];
            unsigned dl = (unsigned)(dst[e] & (BNODES - 1));
            int idx = lofs[b] + r;
            val[idx] = s | (dl << 16);
            bid[idx] = (unsigned char)b;
        }
    }
    __syncthreads();
    // linear write-out: consecutive lanes -> consecutive global addresses within bucket runs
    for (int i = t; i < tot; i += 256) {
        int b = bid[i];
        barr[gbo[b] + hbase[b] + (i - lofs[b])] = val[i];
    }
}

// ---------- pass B: per 256-node bucket, build rowptr + csr via LDS staging ----------
__global__ __launch_bounds__(256) void k_passB(const unsigned* __restrict__ barr, const int* __restrict__ boff,
                                               int* __restrict__ rowptr, int* __restrict__ csr) {
    __shared__ int dcnt[256];
    __shared__ int dsum[256];
    __shared__ int locOff[256];
    __shared__ unsigned stg[PB_CAP];
    int b = blockIdx.x;
    int t = threadIdx.x;
    if (b == 0 && t == 0) rowptr[N_NODES] = E_TOT;
    int n0 = b << BSH;
    int cnt = min(BNODES, N_NODES - n0);
    int eb = boff[b], ee = boff[b + 1];
    int ne = ee - eb;
    dcnt[t] = 0;
    __syncthreads();
    for (int i = eb + t; i < ee; i += 256) atomicAdd(&dcnt[barr[i] >> 16], 1);
    __syncthreads();
    int v = (t < cnt) ? dcnt[t] + 1 : 0;  // +1 self loop
    dsum[t] = v;
    __syncthreads();
    for (int o = 1; o < 256; o <<= 1) {
        int u = (t >= o) ? dsum[t - o] : 0;
        __syncthreads();
        dsum[t] += u;
        __syncthreads();
    }
    int csrBase = eb + n0;
    locOff[t] = dsum[t] - v;
    dcnt[t] = 0;
    if (t < cnt) rowptr[n0 + t] = csrBase + locOff[t];
    int total = ne + cnt;
    __syncthreads();
    if (total <= PB_CAP) {
        if (t < cnt) stg[locOff[t]] = (unsigned)(n0 + t);  // self loop at slot 0
        for (int i = eb + t; i < ee; i += 256) {
            unsigned vv = barr[i];
            int dl = vv >> 16;
            int k = atomicAdd(&dcnt[dl], 1);
            stg[locOff[dl] + 1 + k] = vv & 0xffffu;
        }
        __syncthreads();
        for (int i = t; i < total; i += 256) csr[csrBase + i] = (int)stg[i];
    } else {
        if (t < cnt) csr[csrBase + locOff[t]] = n0 + t;
        for (int i = eb + t; i < ee; i += 256) {
            unsigned vv = barr[i];
            int dl = vv >> 16;
            int k = atomicAdd(&dcnt[dl], 1);
            csr[csrBase + locOff[dl] + 1 + k] = (int)(vv & 0xffffu);
        }
    }
}

// ---------- MFMA GEMM: W fragments straight from global (L2-broadcast), no LDS ----------
template <int K>
__global__ __launch_bounds__(256) void k_mgemm(const unsigned short* __restrict__ Abf,
                                               const unsigned short* __restrict__ WtP,
                                               const float* __restrict__ a_s, const float* __restrict__ a_d,
                                               unsigned short* __restrict__ Hbf,
                                               float* __restrict__ asn, float* __restrict__ adn) {
    constexpr int KP = K + 8;
    constexpr int NK = K / 32;
    int lane = threadIdx.x & 63;
    int wv = threadIdx.x >> 6;
    int rowbase = blockIdx.x * 64 + wv * 16;
    if (rowbase >= N_NODES) return;
    int l15 = lane & 15, quad = lane >> 4;

    const unsigned short* Abase = Abf + (size_t)(rowbase + l15) * K + quad * 8;
    bf16x8 afr[NK];
#pragma unroll
    for (int i = 0; i < NK; i++) afr[i] = *(const bf16x8*)(Abase + i * 32);

    const unsigned short* Wb = WtP + (size_t)l15 * KP + quad * 8;
    f32x4 acc[8];
#pragma unroll
    for (int t = 0; t < 8; t++) acc[t] = (f32x4){0.f, 0.f, 0.f, 0.f};
#pragma unroll
    for (int i = 0; i < NK; i++) {
#pragma unroll
        for (int t = 0; t < 8; t++) {
            bf16x8 bf = *(const bf16x8*)(Wb + (size_t)t * 16 * KP + i * 32);
            acc[t] = __builtin_amdgcn_mfma_f32_16x16x32_bf16(afr[i], bf, acc[t], 0, 0, 0);
        }
    }
    float asc[8], adc[8];
#pragma unroll
    for (int t = 0; t < 8; t++) { asc[t] = a_s[t * 16 + l15]; adc[t] = a_d[t * 16 + l15]; }
#pragma unroll
    for (int r = 0; r < 4; r++) {
        int row = rowbase + quad * 4 + r;
        float ps = 0.f, pd = 0.f;
#pragma unroll
        for (int t = 0; t < 8; t++) {
            float v = acc[t][r];
            Hbf[(size_t)row * HID + t * 16 + l15] = f2bf(v);
            ps = fmaf(v, asc[t], ps);
            pd = fmaf(v, adc[t], pd);
        }
#pragma unroll
        for (int o = 1; o < 16; o <<= 1) {
            ps += __shfl_xor(ps, o);
            pd += __shfl_xor(pd, o);
        }
        if (l15 == 0) { asn[row] = ps; adn[row] = pd; }
    }
}

// ---------- GAT aggregation: 4 waves/block, each wave 4 consecutive nodes ----------
template <bool OUT32>
__global__ __launch_bounds__(256) void k_aggr(const int* __restrict__ rowptr, const int* __restrict__ csr,
                                              const float* __restrict__ asn, const float* __restrict__ adn,
                                              const unsigned short* __restrict__ hbf,
                                              const float* __restrict__ bias, void* __restrict__ outp) {
    __shared__ float sh_e[4][64];
    __shared__ int sh_s[4][64];
    int lane = threadIdx.x & 63;
    int w = threadIdx.x >> 6;
    const unsigned* hu = (const unsigned*)hbf;
    int nodeBase = blockIdx.x * 16 + w * 4;

    for (int it = 0; it < 4; it++) {
        int node = nodeBase + it;
        if (node >= N_NODES) break;
        int st = rowptr[node], en = rowptr[node + 1];
        int deg = en - st;
        float ad = adn[node];
        float2 acc = make_float2(0.f, 0.f);

        if (deg <= 64) {
            int s = 0;
            float l = -1e30f;
            if (lane < deg) {
                s = csr[st + lane];
                l = lrelu02(asn[s] + ad);
            }
            float m = l;
#pragma unroll
            for (int o = 32; o; o >>= 1) m = fmaxf(m, __shfl_xor(m, o));
            float e = (lane < deg) ? __expf(l - m) : 0.f;
            float ssum = e;
#pragma unroll
            for (int o = 32; o; o >>= 1) ssum += __shfl_xor(ssum, o);
            float coef = e / ssum;
            int j = 0;
            for (; j + 8 <= deg; j += 8) {
                int si[8];
                float ci[8];
                unsigned vi[8];
#pragma unroll
                for (int q = 0; q < 8; q++) {
                    si[q] = __builtin_amdgcn_readlane(s, j + q);
                    ci[q] = rl_f(coef, j + q);
                }
#pragma unroll
                for (int q = 0; q < 8; q++) vi[q] = hu[(size_t)si[q] * 64 + lane];
#pragma unroll
                for (int q = 0; q < 8; q++) {
                    acc.x = fmaf(ci[q], __int_as_float(vi[q] << 16), acc.x);
                    acc.y = fmaf(ci[q], __int_as_float(vi[q] & 0xffff0000u), acc.y);
                }
            }
            for (; j + 4 <= deg; j += 4) {
                int s0 = __builtin_amdgcn_readlane(s, j);
                int s1 = __builtin_amdgcn_readlane(s, j + 1);
                int s2 = __builtin_amdgcn_readlane(s, j + 2);
                int s3 = __builtin_amdgcn_readlane(s, j + 3);
                float c0 = rl_f(coef, j), c1 = rl_f(coef, j + 1);
                float c2 = rl_f(coef, j + 2), c3 = rl_f(coef, j + 3);
                unsigned v0 = hu[(size_t)s0 * 64 + lane];
                unsigned v1 = hu[(size_t)s1 * 64 + lane];
                unsigned v2 = hu[(size_t)s2 * 64 + lane];
                unsigned v3 = hu[(size_t)s3 * 64 + lane];
                acc.x = fmaf(c0, __int_as_float(v0 << 16), acc.x);
                acc.y = fmaf(c0, __int_as_float(v0 & 0xffff0000u), acc.y);
                acc.x = fmaf(c1, __int_as_float(v1 << 16), acc.x);
                acc.y = fmaf(c1, __int_as_float(v1 & 0xffff0000u), acc.y);
                acc.x = fmaf(c2, __int_as_float(v2 << 16), acc.x);
                acc.y = fmaf(c2, __int_as_float(v2 & 0xffff0000u), acc.y);
                acc.x = fmaf(c3, __int_as_float(v3 << 16), acc.x);
                acc.y = fmaf(c3, __int_as_float(v3 & 0xffff0000u), acc.y);
            }
            for (; j < deg; j++) {
                int s0 = __builtin_amdgcn_readlane(s, j);
                float c0 = rl_f(coef, j);
                unsigned v0 = hu[(size_t)s0 * 64 + lane];
                acc.x = fmaf(c0, __int_as_float(v0 << 16), acc.x);
                acc.y = fmaf(c0, __int_as_float(v0 & 0xffff0000u), acc.y);
            }
        } else {
            float m = -1e30f;
            for (int i = st + lane; i < en; i += 64) {
                float l = lrelu02(asn[csr[i]] + ad);
                m = fmaxf(m, l);
            }
#pragma unroll
            for (int o = 32; o; o >>= 1) m = fmaxf(m, __shfl_xor(m, o));
            float ssum = 0.f;
            for (int i = st + lane; i < en; i += 64) {
                float l = lrelu02(asn[csr[i]] + ad);
                ssum += __expf(l - m);
            }
#pragma unroll
            for (int o = 32; o; o >>= 1) ssum += __shfl_xor(ssum, o);
            float inv = 1.f / ssum;
            for (int base = st; base < en; base += 64) {
                int cnt = min(64, en - base);
                if (lane < cnt) {
                    int sx = csr[base + lane];
                    float l = lrelu02(asn[sx] + ad);
                    sh_e[w][lane] = __expf(l - m) * inv;
                    sh_s[w][lane] = sx;
                }
                for (int j = 0; j < cnt; j++) {
                    float c = sh_e[w][j];
                    int sx = sh_s[w][j];
                    unsigned v0 = hu[(size_t)sx * 64 + lane];
                    acc.x = fmaf(c, __int_as_float(v0 << 16), acc.x);
                    acc.y = fmaf(c, __int_as_float(v0 & 0xffff0000u), acc.y);
                }
            }
        }
        float2 b = ((const float2*)bias)[lane];
        float rx = gelu_f(acc.x + b.x);
        float ry = gelu_f(acc.y + b.y);
        if constexpr (OUT32) {
            ((float2*)outp)[(size_t)node * 64 + lane] = make_float2(rx, ry);
        } else {
            ((unsigned*)outp)[(size_t)node * 64 + lane] = pk2bf(rx, ry);
        }
    }
}

// ---------- fused global_add_pool + fc + leaky_relu: one block per graph, 512 thr ----------
__global__ __launch_bounds__(512) void k_poolfc(const float* __restrict__ h, const int* __restrict__ batch,
                                                const float* __restrict__ fcW, const float* __restrict__ fcb,
                                                float* __restrict__ out) {
    __shared__ float gv[HID];
    __shared__ float tmp[512];
    int g = blockIdx.x;
    int st, en;
    {
        int lo = 0, hi = N_NODES;
        while (lo < hi) { int mid = (lo + hi) >> 1; if (batch[mid] < g) lo = mid + 1; else hi = mid; }
        st = lo;
        lo = st; hi = N_NODES;
        while (lo < hi) { int mid = (lo + hi) >> 1; if (batch[mid] < g + 1) lo = mid + 1; else hi = mid; }
        en = lo;
    }
    int c = threadIdx.x & 127;
    int part = threadIdx.x >> 7;  // 4-way row parallel
    float acc = 0.f;
#pragma unroll 4
    for (int n = st + part; n < en; n += 4) acc += h[(size_t)n * HID + c];
    tmp[threadIdx.x] = acc;
    __syncthreads();
    if (threadIdx.x < HID)
        gv[threadIdx.x] = tmp[threadIdx.x] + tmp[threadIdx.x + 128] + tmp[threadIdx.x + 256] + tmp[threadIdx.x + 384];
    __syncthreads();
    if (threadIdx.x < OUT_DIM) {
        float a = fcb[threadIdx.x];
#pragma unroll 4
        for (int k = 0; k < HID; k++) a = fmaf(gv[k], fcW[k * OUT_DIM + threadIdx.x], a);
        out[g * OUT_DIM + threadIdx.x] = a > 0.f ? a : 0.01f * a;
    }
}

extern "C" void kernel_launch(void* const* d_in, const int* in_sizes, int n_in,
                              void* d_out, int out_size, void* d_ws, size_t ws_size,
                              hipStream_t stream) {
    const float* x    = (const float*)d_in[0];
    const int* nidx   = (const int*)d_in[1];
    const int* ei     = (const int*)d_in[2];
    const int* batch  = (const int*)d_in[3];
    const float* emb  = (const float*)d_in[4];
    const float* W1   = (const float*)d_in[5];
    const float* a1s  = (const float*)d_in[6];
    const float* a1d  = (const float*)d_in[7];
    const float* b1   = (const float*)d_in[8];
    const float* W2   = (const float*)d_in[9];
    const float* a2s  = (const float*)d_in[10];
    const float* a2d  = (const float*)d_in[11];
    const float* b2   = (const float*)d_in[12];
    const float* W3   = (const float*)d_in[13];
    const float* a3s  = (const float*)d_in[14];
    const float* a3d  = (const float*)d_in[15];
    const float* b3   = (const float*)d_in[16];
    const float* fcW  = (const float*)d_in[17];
    const float* fcb  = (const float*)d_in[18];
    float* out = (float*)d_out;
    const int* srcA = ei;
    const int* dstA = ei + N_EDGES;

    char* w = (char*)d_ws;
    auto alloc = [&](size_t bytes) -> char* {
        char* p = w;
        w += (bytes + 511) & ~(size_t)511;
        return p;
    };
    // region0: Abf [N,192] bf16 during prep+GEMM1; later h3f fp32 [N,128]
    char* region0 = alloc((size_t)N_NODES * HID * 4);
    unsigned* Abu = (unsigned*)region0;
    float* h3f    = (float*)region0;
    unsigned short* hLin = (unsigned short*)alloc((size_t)N_NODES * HID * 2);
    unsigned short* hAct = (unsigned short*)alloc((size_t)N_NODES * HID * 2);
    float* asn   = (float*)alloc((size_t)N_NODES * 4);
    float* adn   = (float*)alloc((size_t)N_NODES * 4);
    int* rowptr  = (int*)alloc((size_t)(N_NODES + 1) * 4);
    int* bcnt    = (int*)alloc((size_t)NB * 4);
    int* boff    = (int*)alloc((size_t)(NB + 1) * 4);
    int* bfill   = (int*)alloc((size_t)NB * 4);
    unsigned* barr = (unsigned*)alloc((size_t)N_EDGES * 4);
    int* csr     = (int*)alloc((size_t)E_TOT * 4);
    unsigned short* Wt1 = (unsigned short*)alloc((size_t)HID * (K1 + 8) * 2);
    unsigned short* Wt2 = (unsigned short*)alloc((size_t)HID * (HID + 8) * 2);
    unsigned short* Wt3 = (unsigned short*)alloc((size_t)HID * (HID + 8) * 2);

    k_prepW3<<<K1 + 2 * HID + 1, 128, 0, stream>>>(W1, Wt1, W2, Wt2, W3, Wt3, bcnt, bfill);
    k_prepA_bhist<<<PREPA_BLOCKS + BHIST_BLOCKS, 256, 0, stream>>>(x, nidx, emb, Abu, dstA, bcnt);

    k_passA<<<(N_EDGES + EPB - 1) / EPB, 256, 0, stream>>>(srcA, dstA, bcnt, boff, bfill, barr);
    k_passB<<<NB, 256, 0, stream>>>(barr, boff, rowptr, csr);

    int gemmBlocks = (N_NODES + 63) / 64;  // 782

    k_mgemm<K1><<<gemmBlocks, 256, 0, stream>>>((const unsigned short*)Abu, Wt1, a1s, a1d, hLin, asn, adn);
    k_aggr<false><<<AGGR_BLOCKS, 256, 0, stream>>>(rowptr, csr, asn, adn, hLin, b1, hAct);
    k_mgemm<HID><<<gemmBlocks, 256, 0, stream>>>(hAct, Wt2, a2s, a2d, hLin, asn, adn);
    k_aggr<false><<<AGGR_BLOCKS, 256, 0, stream>>>(rowptr, csr, asn, adn, hLin, b2, hAct);
    k_mgemm<HID><<<gemmBlocks, 256, 0, stream>>>(hAct, Wt3, a3s, a3d, hLin, asn, adn);
    k_aggr<true><<<AGGR_BLOCKS, 256, 0, stream>>>(rowptr, csr, asn, adn, hLin, b3, h3f);

    k_poolfc<<<NUM_GRAPHS, 512, 0, stream>>>(h3f, batch, fcW, fcb, out);
}

// Round 9
// 323.387 us; speedup vs baseline: 1.0467x; 1.0467x over previous
//
#include <hip/hip_runtime.h>

#define N_NODES 50000
#define N_EDGES 800000
#define IN_DIM 128
#define EMB_DIM 64
#define HID 128
#define OUT_DIM 64
#define NUM_GRAPHS 128
#define E_TOT (N_EDGES + N_NODES)
#define K1 (IN_DIM + EMB_DIM)   // 192
#define BSH 8                    // bucket = 256 dst nodes
#define BNODES 256
#define NB 196                   // ceil(N_NODES/256)
#define EPT 8
#define EPB (256 * EPT)          // 2048 edges per passA block (391 blocks, ~14KB LDS)
#define PREPA_BLOCKS 3125        // 16 nodes per block
#define BHIST_BLOCKS 512
#define PB_CAP 5376              // passB LDS staging capacity
#define AGGR_BLOCKS 3125         // 16 nodes per block (4 waves x 4 nodes), exact

typedef __attribute__((ext_vector_type(8))) short bf16x8;
typedef __attribute__((ext_vector_type(4))) float f32x4;

__device__ __forceinline__ float gelu_f(float x) {
    float x3 = x * x * x;
    return 0.5f * x * (1.0f + tanhf(0.7978845608028654f * (x + 0.044715f * x3)));
}
__device__ __forceinline__ float lrelu02(float x) { return x > 0.f ? x : 0.2f * x; }
__device__ __forceinline__ float rl_f(float v, int j) {
    return __int_as_float(__builtin_amdgcn_readlane(__float_as_int(v), j));
}
__device__ __forceinline__ unsigned short f2bf(float f) {  // RNE
    unsigned u = __float_as_uint(f);
    unsigned r = (u + 0x7fffu + ((u >> 16) & 1u)) >> 16;
    return (unsigned short)r;
}
__device__ __forceinline__ unsigned pk2bf(float a, float b) {
    return (unsigned)f2bf(a) | ((unsigned)f2bf(b) << 16);
}

// ---------- prep all three W^T bf16 padded; last block zeroes bcnt/bfill ----------
__global__ __launch_bounds__(128) void k_prepW3(const float* __restrict__ W1, unsigned short* __restrict__ Wt1,
                                                const float* __restrict__ W2, unsigned short* __restrict__ Wt2,
                                                const float* __restrict__ W3, unsigned short* __restrict__ Wt3,
                                                int* __restrict__ bcnt, int* __restrict__ bfill) {
    int b = blockIdx.x;
    int c = threadIdx.x;
    if (b == K1 + 2 * HID) {
        for (int i = c; i < NB; i += 128) { bcnt[i] = 0; bfill[i] = 0; }
        return;
    }
    if (b < K1) {
        Wt1[(size_t)c * (K1 + 8) + b] = f2bf(W1[(size_t)b * HID + c]);
    } else if (b < K1 + HID) {
        int k = b - K1;
        Wt2[(size_t)c * (HID + 8) + k] = f2bf(W2[(size_t)k * HID + c]);
    } else {
        int k = b - K1 - HID;
        Wt3[(size_t)c * (HID + 8) + k] = f2bf(W3[(size_t)k * HID + c]);
    }
}

// ---------- prep A: 16 nodes/block (4 waves x 4 nodes) + bucket histogram tail ----------
__global__ __launch_bounds__(256) void k_prepA_bhist(const float* __restrict__ x, const int* __restrict__ nidx,
                                                     const float* __restrict__ emb, unsigned* __restrict__ Abu,
                                                     const int* __restrict__ dst, int* __restrict__ bcnt) {
    __shared__ int h[NB];
    if (blockIdx.x >= PREPA_BLOCKS) {
        int nb = blockIdx.x - PREPA_BLOCKS;
        for (int i = threadIdx.x; i < NB; i += 256) h[i] = 0;
        __syncthreads();
        for (int e = nb * 256 + threadIdx.x; e < N_EDGES; e += BHIST_BLOCKS * 256)
            atomicAdd(&h[dst[e] >> BSH], 1);
        __syncthreads();
        for (int i = threadIdx.x; i < NB; i += 256)
            if (h[i]) atomicAdd(&bcnt[i], h[i]);
        return;
    }
    int lane = threadIdx.x & 63;
    int wv = threadIdx.x >> 6;
    int nodeBase = blockIdx.x * 16 + wv * 4;
#pragma unroll
    for (int it = 0; it < 4; it++) {
        int node = nodeBase + it;
        int nid = nidx[node];  // issue early: overlaps with x-row load below
        float2 v = ((const float2*)(x + (size_t)node * IN_DIM))[lane];
        float ss = v.x * v.x + v.y * v.y;
#pragma unroll
        for (int o = 32; o; o >>= 1) ss += __shfl_xor(ss, o);
        float nrm = sqrtf(ss);
        if (nrm == 0.f) nrm = 1e-8f;
        float inv = 1.f / nrm;
        unsigned* row = Abu + (size_t)node * (K1 / 2);
        row[lane] = pk2bf(v.x * inv, v.y * inv);
        nid = __builtin_amdgcn_readfirstlane(nid);
        if (lane < 32) {
            float2 e = ((const float2*)(emb + (size_t)nid * EMB_DIM))[lane];
            row[64 + lane] = pk2bf(e.x, e.y);
        }
    }
}

// ---------- pass A: partition edges bucket-major; local scan (bscan folded in) ----------
__global__ __launch_bounds__(256) void k_passA(const int* __restrict__ src, const int* __restrict__ dst,
                                               const int* __restrict__ bcnt, int* __restrict__ boff,
                                               int* __restrict__ bfill, unsigned* __restrict__ barr) {
    __shared__ int h[NB];
    __shared__ int hbase[NB];
    __shared__ int lofs[NB];
    __shared__ int gbo[NB];      // global bucket offsets (local scan of bcnt)
    __shared__ int ssc[256];
    __shared__ unsigned val[EPB];
    __shared__ unsigned char bid[EPB];
    int t = threadIdx.x;
    for (int i = t; i < NB; i += 256) h[i] = 0;
    // scan bcnt -> gbo (every block computes identical result; replaces k_bscan)
    int gv = (t < NB) ? bcnt[t] : 0;
    ssc[t] = gv;
    __syncthreads();
    for (int o = 1; o < 256; o <<= 1) {
        int u = (t >= o) ? ssc[t - o] : 0;
        __syncthreads();
        ssc[t] += u;
        __syncthreads();
    }
    if (t < NB) gbo[t] = ssc[t] - gv;
    if (blockIdx.x == 0) {
        if (t < NB) boff[t] = ssc[t] - gv;
        if (t == NB - 1) boff[NB] = ssc[t];
    }
    __syncthreads();
    int e0 = blockIdx.x * EPB;
    int tag[EPT];
#pragma unroll
    for (int i = 0; i < EPT; i++) {
        int e = e0 + i * 256 + t;
        tag[i] = -1;
        if (e < N_EDGES) {
            int b = dst[e] >> BSH;
            int r = atomicAdd(&h[b], 1);  // rank within (block,bucket); r < 2048
            tag[i] = (b << 12) | r;
        }
    }
    __syncthreads();
    // exclusive scan of per-bucket LOCAL counts -> local offsets; claim global chunks
    int v = (t < NB) ? h[t] : 0;
    ssc[t] = v;
    __syncthreads();
    for (int o = 1; o < 256; o <<= 1) {
        int u = (t >= o) ? ssc[t - o] : 0;
        __syncthreads();
        ssc[t] += u;
        __syncthreads();
    }
    if (t < NB) {
        lofs[t] = ssc[t] - v;
        hbase[t] = v ? atomicAdd(&bfill[t], v) : 0;
    }
    __syncthreads();
    int tot = ssc[255];
    // scatter into LDS (bucket-major within block)
#pragma unroll
    for (int i = 0; i < EPT; i++) {
        if (tag[i] >= 0) {
            int e = e0 + i * 256 + t;
            int b = tag[i] >> 12, r = tag[i] & 0xfff;
            unsigned s = (unsigned)src[e];
            unsigned dl = (unsigned)(dst[e] & (BNODES - 1));
            int idx = lofs[b] + r;
            val[idx] = s | (dl << 16);
            bid[idx] = (unsigned char)b;
        }
    }
    __syncthreads();
    // linear write-out: consecutive lanes -> consecutive global addresses within bucket runs
    for (int i = t; i < tot; i += 256) {
        int b = bid[i];
        barr[gbo[b] + hbase[b] + (i - lofs[b])] = val[i];
    }
}

// ---------- pass B: per 256-node bucket, build rowptr + csr via LDS staging ----------
__global__ __launch_bounds__(256) void k_passB(const unsigned* __restrict__ barr, const int* __restrict__ boff,
                                               int* __restrict__ rowptr, int* __restrict__ csr) {
    __shared__ int dcnt[256];
    __shared__ int dsum[256];
    __shared__ int locOff[256];
    __shared__ unsigned stg[PB_CAP];
    int b = blockIdx.x;
    int t = threadIdx.x;
    if (b == 0 && t == 0) rowptr[N_NODES] = E_TOT;
    int n0 = b << BSH;
    int cnt = min(BNODES, N_NODES - n0);
    int eb = boff[b], ee = boff[b + 1];
    int ne = ee - eb;
    dcnt[t] = 0;
    __syncthreads();
    for (int i = eb + t; i < ee; i += 256) atomicAdd(&dcnt[barr[i] >> 16], 1);
    __syncthreads();
    int v = (t < cnt) ? dcnt[t] + 1 : 0;  // +1 self loop
    dsum[t] = v;
    __syncthreads();
    for (int o = 1; o < 256; o <<= 1) {
        int u = (t >= o) ? dsum[t - o] : 0;
        __syncthreads();
        dsum[t] += u;
        __syncthreads();
    }
    int csrBase = eb + n0;
    locOff[t] = dsum[t] - v;
    dcnt[t] = 0;
    if (t < cnt) rowptr[n0 + t] = csrBase + locOff[t];
    int total = ne + cnt;
    __syncthreads();
    if (total <= PB_CAP) {
        if (t < cnt) stg[locOff[t]] = (unsigned)(n0 + t);  // self loop at slot 0
        for (int i = eb + t; i < ee; i += 256) {
            unsigned vv = barr[i];
            int dl = vv >> 16;
            int k = atomicAdd(&dcnt[dl], 1);
            stg[locOff[dl] + 1 + k] = vv & 0xffffu;
        }
        __syncthreads();
        for (int i = t; i < total; i += 256) csr[csrBase + i] = (int)stg[i];
    } else {
        if (t < cnt) csr[csrBase + locOff[t]] = n0 + t;
        for (int i = eb + t; i < ee; i += 256) {
            unsigned vv = barr[i];
            int dl = vv >> 16;
            int k = atomicAdd(&dcnt[dl], 1);
            csr[csrBase + locOff[dl] + 1 + k] = (int)(vv & 0xffffu);
        }
    }
}

// ---------- MFMA GEMM: W fragments straight from global (L2-broadcast), no LDS ----------
template <int K>
__global__ __launch_bounds__(256) void k_mgemm(const unsigned short* __restrict__ Abf,
                                               const unsigned short* __restrict__ WtP,
                                               const float* __restrict__ a_s, const float* __restrict__ a_d,
                                               unsigned short* __restrict__ Hbf,
                                               float* __restrict__ asn, float* __restrict__ adn) {
    constexpr int KP = K + 8;
    constexpr int NK = K / 32;
    int lane = threadIdx.x & 63;
    int wv = threadIdx.x >> 6;
    int rowbase = blockIdx.x * 64 + wv * 16;
    if (rowbase >= N_NODES) return;
    int l15 = lane & 15, quad = lane >> 4;

    const unsigned short* Abase = Abf + (size_t)(rowbase + l15) * K + quad * 8;
    bf16x8 afr[NK];
#pragma unroll
    for (int i = 0; i < NK; i++) afr[i] = *(const bf16x8*)(Abase + i * 32);

    const unsigned short* Wb = WtP + (size_t)l15 * KP + quad * 8;
    f32x4 acc[8];
#pragma unroll
    for (int t = 0; t < 8; t++) acc[t] = (f32x4){0.f, 0.f, 0.f, 0.f};
#pragma unroll
    for (int i = 0; i < NK; i++) {
#pragma unroll
        for (int t = 0; t < 8; t++) {
            bf16x8 bf = *(const bf16x8*)(Wb + (size_t)t * 16 * KP + i * 32);
            acc[t] = __builtin_amdgcn_mfma_f32_16x16x32_bf16(afr[i], bf, acc[t], 0, 0, 0);
        }
    }
    float asc[8], adc[8];
#pragma unroll
    for (int t = 0; t < 8; t++) { asc[t] = a_s[t * 16 + l15]; adc[t] = a_d[t * 16 + l15]; }
#pragma unroll
    for (int r = 0; r < 4; r++) {
        int row = rowbase + quad * 4 + r;
        float ps = 0.f, pd = 0.f;
#pragma unroll
        for (int t = 0; t < 8; t++) {
            float v = acc[t][r];
            Hbf[(size_t)row * HID + t * 16 + l15] = f2bf(v);
            ps = fmaf(v, asc[t], ps);
            pd = fmaf(v, adc[t], pd);
        }
#pragma unroll
        for (int o = 1; o < 16; o <<= 1) {
            ps += __shfl_xor(ps, o);
            pd += __shfl_xor(pd, o);
        }
        if (l15 == 0) { asn[row] = ps; adn[row] = pd; }
    }
}

// ---------- GAT aggregation: 4 waves/block, 4 nodes/wave, softmax-phase pipelined ----------
template <bool OUT32>
__global__ __launch_bounds__(256) void k_aggr(const int* __restrict__ rowptr, const int* __restrict__ csr,
                                              const float* __restrict__ asn, const float* __restrict__ adn,
                                              const unsigned short* __restrict__ hbf,
                                              const float* __restrict__ bias, void* __restrict__ outp) {
    __shared__ float sh_e[4][64];
    __shared__ int sh_s[4][64];
    int lane = threadIdx.x & 63;
    int w = threadIdx.x >> 6;
    const unsigned* hu = (const unsigned*)hbf;
    int nodeBase = blockIdx.x * 16 + w * 4;   // grid exact: 3125*16 == N_NODES

    // one 5-wide rowptr load + 4-wide adn load serve all 4 nodes
    int r0 = (lane < 5) ? rowptr[nodeBase + lane] : 0;
    float adv = (lane < 4) ? adn[nodeBase + lane] : 0.f;
    float2 bb = ((const float2*)bias)[lane];
    int stA[4], degA[4];
#pragma unroll
    for (int it = 0; it < 4; it++) {
        stA[it] = __builtin_amdgcn_readlane(r0, it);
        degA[it] = __builtin_amdgcn_readlane(r0, it + 1) - stA[it];
    }
    bool fast = degA[0] <= 64 && degA[1] <= 64 && degA[2] <= 64 && degA[3] <= 64;

    if (fast) {
        // phase 1: 4 independent csr row loads in flight
        int s4[4];
#pragma unroll
        for (int it = 0; it < 4; it++) s4[it] = (lane < degA[it]) ? csr[stA[it] + lane] : 0;
        // phase 2: 4 independent asn gathers in flight
        float l4[4];
#pragma unroll
        for (int it = 0; it < 4; it++) {
            float a = asn[s4[it]];
            l4[it] = (lane < degA[it]) ? lrelu02(a + rl_f(adv, it)) : -1e30f;
        }
        // phase 3: VALU-only softmax reductions
        float coef4[4];
#pragma unroll
        for (int it = 0; it < 4; it++) {
            float m = l4[it];
#pragma unroll
            for (int o = 32; o; o >>= 1) m = fmaxf(m, __shfl_xor(m, o));
            float e = (lane < degA[it]) ? __expf(l4[it] - m) : 0.f;
            float ssum = e;
#pragma unroll
            for (int o = 32; o; o >>= 1) ssum += __shfl_xor(ssum, o);
            coef4[it] = e / ssum;
        }
        // phase 4: back-to-back gather-FMA bursts (proven r1 inner loop)
#pragma unroll
        for (int it = 0; it < 4; it++) {
            int node = nodeBase + it;
            int deg = degA[it];
            int s = s4[it];
            float coef = coef4[it];
            float2 acc = make_float2(0.f, 0.f);
            int j = 0;
            for (; j + 8 <= deg; j += 8) {
                int si[8];
                float ci[8];
                unsigned vi[8];
#pragma unroll
                for (int q = 0; q < 8; q++) {
                    si[q] = __builtin_amdgcn_readlane(s, j + q);
                    ci[q] = rl_f(coef, j + q);
                }
#pragma unroll
                for (int q = 0; q < 8; q++) vi[q] = hu[(size_t)si[q] * 64 + lane];
#pragma unroll
                for (int q = 0; q < 8; q++) {
                    acc.x = fmaf(ci[q], __int_as_float(vi[q] << 16), acc.x);
                    acc.y = fmaf(ci[q], __int_as_float(vi[q] & 0xffff0000u), acc.y);
                }
            }
            for (; j + 4 <= deg; j += 4) {
                int s0 = __builtin_amdgcn_readlane(s, j);
                int s1 = __builtin_amdgcn_readlane(s, j + 1);
                int s2 = __builtin_amdgcn_readlane(s, j + 2);
                int s3 = __builtin_amdgcn_readlane(s, j + 3);
                float c0 = rl_f(coef, j), c1 = rl_f(coef, j + 1);
                float c2 = rl_f(coef, j + 2), c3 = rl_f(coef, j + 3);
                unsigned v0 = hu[(size_t)s0 * 64 + lane];
                unsigned v1 = hu[(size_t)s1 * 64 + lane];
                unsigned v2 = hu[(size_t)s2 * 64 + lane];
                unsigned v3 = hu[(size_t)s3 * 64 + lane];
                acc.x = fmaf(c0, __int_as_float(v0 << 16), acc.x);
                acc.y = fmaf(c0, __int_as_float(v0 & 0xffff0000u), acc.y);
                acc.x = fmaf(c1, __int_as_float(v1 << 16), acc.x);
                acc.y = fmaf(c1, __int_as_float(v1 & 0xffff0000u), acc.y);
                acc.x = fmaf(c2, __int_as_float(v2 << 16), acc.x);
                acc.y = fmaf(c2, __int_as_float(v2 & 0xffff0000u), acc.y);
                acc.x = fmaf(c3, __int_as_float(v3 << 16), acc.x);
                acc.y = fmaf(c3, __int_as_float(v3 & 0xffff0000u), acc.y);
            }
            for (; j < deg; j++) {
                int s0 = __builtin_amdgcn_readlane(s, j);
                float c0 = rl_f(coef, j);
                unsigned v0 = hu[(size_t)s0 * 64 + lane];
                acc.x = fmaf(c0, __int_as_float(v0 << 16), acc.x);
                acc.y = fmaf(c0, __int_as_float(v0 & 0xffff0000u), acc.y);
            }
            float rx = gelu_f(acc.x + bb.x);
            float ry = gelu_f(acc.y + bb.y);
            if constexpr (OUT32) {
                ((float2*)outp)[(size_t)node * 64 + lane] = make_float2(rx, ry);
            } else {
                ((unsigned*)outp)[(size_t)node * 64 + lane] = pk2bf(rx, ry);
            }
        }
    } else {
        // rare: at least one node with deg>64 — process all 4 sequentially (old path)
        for (int it = 0; it < 4; it++) {
            int node = nodeBase + it;
            int st = stA[it], deg = degA[it];
            int en = st + deg;
            float ad = rl_f(adv, it);
            float2 acc = make_float2(0.f, 0.f);
            if (deg <= 64) {
                int s = 0;
                float l = -1e30f;
                if (lane < deg) {
                    s = csr[st + lane];
                    l = lrelu02(asn[s] + ad);
                }
                float m = l;
#pragma unroll
                for (int o = 32; o; o >>= 1) m = fmaxf(m, __shfl_xor(m, o));
                float e = (lane < deg) ? __expf(l - m) : 0.f;
                float ssum = e;
#pragma unroll
                for (int o = 32; o; o >>= 1) ssum += __shfl_xor(ssum, o);
                float coef = e / ssum;
                for (int j = 0; j < deg; j++) {
                    int s0 = __builtin_amdgcn_readlane(s, j);
                    float c0 = rl_f(coef, j);
                    unsigned v0 = hu[(size_t)s0 * 64 + lane];
                    acc.x = fmaf(c0, __int_as_float(v0 << 16), acc.x);
                    acc.y = fmaf(c0, __int_as_float(v0 & 0xffff0000u), acc.y);
                }
            } else {
                float m = -1e30f;
                for (int i = st + lane; i < en; i += 64) {
                    float l = lrelu02(asn[csr[i]] + ad);
                    m = fmaxf(m, l);
                }
#pragma unroll
                for (int o = 32; o; o >>= 1) m = fmaxf(m, __shfl_xor(m, o));
                float ssum = 0.f;
                for (int i = st + lane; i < en; i += 64) {
                    float l = lrelu02(asn[csr[i]] + ad);
                    ssum += __expf(l - m);
                }
#pragma unroll
                for (int o = 32; o; o >>= 1) ssum += __shfl_xor(ssum, o);
                float inv = 1.f / ssum;
                for (int base = st; base < en; base += 64) {
                    int cnt = min(64, en - base);
                    if (lane < cnt) {
                        int sx = csr[base + lane];
                        float l = lrelu02(asn[sx] + ad);
                        sh_e[w][lane] = __expf(l - m) * inv;
                        sh_s[w][lane] = sx;
                    }
                    for (int j = 0; j < cnt; j++) {
                        float c = sh_e[w][j];
                        int sx = sh_s[w][j];
                        unsigned v0 = hu[(size_t)sx * 64 + lane];
                        acc.x = fmaf(c, __int_as_float(v0 << 16), acc.x);
                        acc.y = fmaf(c, __int_as_float(v0 & 0xffff0000u), acc.y);
                    }
                }
            }
            float rx = gelu_f(acc.x + bb.x);
            float ry = gelu_f(acc.y + bb.y);
            if constexpr (OUT32) {
                ((float2*)outp)[(size_t)node * 64 + lane] = make_float2(rx, ry);
            } else {
                ((unsigned*)outp)[(size_t)node * 64 + lane] = pk2bf(rx, ry);
            }
        }
    }
}

// ---------- fused global_add_pool + fc + leaky_relu: one block per graph, 512 thr ----------
__global__ __launch_bounds__(512) void k_poolfc(const float* __restrict__ h, const int* __restrict__ batch,
                                                const float* __restrict__ fcW, const float* __restrict__ fcb,
                                                float* __restrict__ out) {
    __shared__ float gv[HID];
    __shared__ float tmp[512];
    int g = blockIdx.x;
    int st, en;
    {
        int lo = 0, hi = N_NODES;
        while (lo < hi) { int mid = (lo + hi) >> 1; if (batch[mid] < g) lo = mid + 1; else hi = mid; }
        st = lo;
        lo = st; hi = N_NODES;
        while (lo < hi) { int mid = (lo + hi) >> 1; if (batch[mid] < g + 1) lo = mid + 1; else hi = mid; }
        en = lo;
    }
    int c = threadIdx.x & 127;
    int part = threadIdx.x >> 7;  // 4-way row parallel
    float acc = 0.f;
#pragma unroll 4
    for (int n = st + part; n < en; n += 4) acc += h[(size_t)n * HID + c];
    tmp[threadIdx.x] = acc;
    __syncthreads();
    if (threadIdx.x < HID)
        gv[threadIdx.x] = tmp[threadIdx.x] + tmp[threadIdx.x + 128] + tmp[threadIdx.x + 256] + tmp[threadIdx.x + 384];
    __syncthreads();
    if (threadIdx.x < OUT_DIM) {
        float a = fcb[threadIdx.x];
#pragma unroll 4
        for (int k = 0; k < HID; k++) a = fmaf(gv[k], fcW[k * OUT_DIM + threadIdx.x], a);
        out[g * OUT_DIM + threadIdx.x] = a > 0.f ? a : 0.01f * a;
    }
}

extern "C" void kernel_launch(void* const* d_in, const int* in_sizes, int n_in,
                              void* d_out, int out_size, void* d_ws, size_t ws_size,
                              hipStream_t stream) {
    const float* x    = (const float*)d_in[0];
    const int* nidx   = (const int*)d_in[1];
    const int* ei     = (const int*)d_in[2];
    const int* batch  = (const int*)d_in[3];
    const float* emb  = (const float*)d_in[4];
    const float* W1   = (const float*)d_in[5];
    const float* a1s  = (const float*)d_in[6];
    const float* a1d  = (const float*)d_in[7];
    const float* b1   = (const float*)d_in[8];
    const float* W2   = (const float*)d_in[9];
    const float* a2s  = (const float*)d_in[10];
    const float* a2d  = (const float*)d_in[11];
    const float* b2   = (const float*)d_in[12];
    const float* W3   = (const float*)d_in[13];
    const float* a3s  = (const float*)d_in[14];
    const float* a3d  = (const float*)d_in[15];
    const float* b3   = (const float*)d_in[16];
    const float* fcW  = (const float*)d_in[17];
    const float* fcb  = (const float*)d_in[18];
    float* out = (float*)d_out;
    const int* srcA = ei;
    const int* dstA = ei + N_EDGES;

    char* w = (char*)d_ws;
    auto alloc = [&](size_t bytes) -> char* {
        char* p = w;
        w += (bytes + 511) & ~(size_t)511;
        return p;
    };
    // region0: Abf [N,192] bf16 during prep+GEMM1; later h3f fp32 [N,128]
    char* region0 = alloc((size_t)N_NODES * HID * 4);
    unsigned* Abu = (unsigned*)region0;
    float* h3f    = (float*)region0;
    unsigned short* hLin = (unsigned short*)alloc((size_t)N_NODES * HID * 2);
    unsigned short* hAct = (unsigned short*)alloc((size_t)N_NODES * HID * 2);
    float* asn   = (float*)alloc((size_t)N_NODES * 4);
    float* adn   = (float*)alloc((size_t)N_NODES * 4);
    int* rowptr  = (int*)alloc((size_t)(N_NODES + 1) * 4);
    int* bcnt    = (int*)alloc((size_t)NB * 4);
    int* boff    = (int*)alloc((size_t)(NB + 1) * 4);
    int* bfill   = (int*)alloc((size_t)NB * 4);
    unsigned* barr = (unsigned*)alloc((size_t)N_EDGES * 4);
    int* csr     = (int*)alloc((size_t)E_TOT * 4);
    unsigned short* Wt1 = (unsigned short*)alloc((size_t)HID * (K1 + 8) * 2);
    unsigned short* Wt2 = (unsigned short*)alloc((size_t)HID * (HID + 8) * 2);
    unsigned short* Wt3 = (unsigned short*)alloc((size_t)HID * (HID + 8) * 2);

    k_prepW3<<<K1 + 2 * HID + 1, 128, 0, stream>>>(W1, Wt1, W2, Wt2, W3, Wt3, bcnt, bfill);
    k_prepA_bhist<<<PREPA_BLOCKS + BHIST_BLOCKS, 256, 0, stream>>>(x, nidx, emb, Abu, dstA, bcnt);

    k_passA<<<(N_EDGES + EPB - 1) / EPB, 256, 0, stream>>>(srcA, dstA, bcnt, boff, bfill, barr);
    k_passB<<<NB, 256, 0, stream>>>(barr, boff, rowptr, csr);

    int gemmBlocks = (N_NODES + 63) / 64;  // 782

    k_mgemm<K1><<<gemmBlocks, 256, 0, stream>>>((const unsigned short*)Abu, Wt1, a1s, a1d, hLin, asn, adn);
    k_aggr<false><<<AGGR_BLOCKS, 256, 0, stream>>>(rowptr, csr, asn, adn, hLin, b1, hAct);
    k_mgemm<HID><<<gemmBlocks, 256, 0, stream>>>(hAct, Wt2, a2s, a2d, hLin, asn, adn);
    k_aggr<false><<<AGGR_BLOCKS, 256, 0, stream>>>(rowptr, csr, asn, adn, hLin, b2, hAct);
    k_mgemm<HID><<<gemmBlocks, 256, 0, stream>>>(hAct, Wt3, a3s, a3d, hLin, asn, adn);
    k_aggr<true><<<AGGR_BLOCKS, 256, 0, stream>>>(rowptr, csr, asn, adn, hLin, b3, h3f);

    k_poolfc<<<NUM_GRAPHS, 512, 0, stream>>>(h3f, batch, fcW, fcb, out);
}